// Round 21
// baseline (65.108 us; speedup 1.0000x reference)
//
#include <hip/hip_runtime.h>
#include <hip/hip_bf16.h>

// SelfAttention: B=2, S=2048, E=1024, H=16, D=64
// R21: R20 base (best: 64.90 us) with ONE change — attn processes 2 k-tiles
// per barrier (quad-buffered pairs; prefetch pair p^1 while computing pair p).
// Retests the barrier-count theory on the clean 8-wave base (R9's null was on
// the old 4-wave base where proj/outproj overheads masked attn).
//   prep    : 2 blocks, per-batch mask scan -> g_srcidx/g_NK
//   proj    : K(compacted), Q(pre-scaled log2e/32), V(compacted,T), Wo->bf16
//   attn    : swapped-QK^T, 32x32x16 MFMA, m=0, gll quad-buf (2 tiles/barrier),
//             8-wave 256q blocks, XCD swizzle, setprio
//   outproj : [4096,1024] @ WoB^T + bo -> f32, 128^2 tile, XCD swizzle

typedef __attribute__((ext_vector_type(8))) short bf16x8;
typedef __attribute__((ext_vector_type(4))) float f32x4;
typedef __attribute__((ext_vector_type(16))) float f32x16;
typedef __attribute__((ext_vector_type(2))) int i32x2;

__device__ int g_srcidx[2 * 2048];
__device__ int g_NK[2];

__device__ __forceinline__ short f2bf(float x) {
  union { float f; unsigned u; } v; v.f = x;
  unsigned r = v.u + 0x7FFFu + ((v.u >> 16) & 1u);
  return (short)(r >> 16);
}

// pair pack via compiler-recognized cast -> v_cvt_pk_bf16_f32 (RNE)
__device__ __forceinline__ int pack2(float lo, float hi) {
  __hip_bfloat162 h = __float22bfloat162_rn(make_float2(lo, hi));
  int r; __builtin_memcpy(&r, &h, 4); return r;
}

__device__ __forceinline__ bf16x8 cvt8(float4 a, float4 b) {
  union { int i[4]; bf16x8 h; } u;
  u.i[0] = pack2(a.x, a.y);
  u.i[1] = pack2(a.z, a.w);
  u.i[2] = pack2(b.x, b.y);
  u.i[3] = pack2(b.z, b.w);
  return u.h;
}

__device__ __forceinline__ void plsw(int& a, int& b) {
  i32x2 r = __builtin_amdgcn_permlane32_swap(a, b, false, false);
  a = r[0]; b = r[1];
}
__device__ __forceinline__ float pl_comb_add(float v) {
  int a = __float_as_int(v), b = a;
  i32x2 r = __builtin_amdgcn_permlane32_swap(a, b, false, false);
  return __int_as_float(r[0]) + __int_as_float(r[1]);
}

// async global->LDS, 16B per lane; LDS dest must be wave-linear (base+lane*16)
__device__ __forceinline__ void gll16(const short* g, short* l) {
  __builtin_amdgcn_global_load_lds(
      (const __attribute__((address_space(1))) void*)g,
      (__attribute__((address_space(3))) void*)l, 16, 0, 0);
}

// ---------------------------------------------------------------------------
// prep: per-batch mask scan only (2 blocks).
// ---------------------------------------------------------------------------
__global__ __launch_bounds__(256) void prep_kernel(const int* __restrict__ mask) {
  __shared__ int cnt[256];
  const int t = threadIdx.x;
  const int b = blockIdx.x;
  const int* m = mask + b * 2048;
  int* sidx = g_srcidx + b * 2048;
  const int base = t * 8;
  int vals[8], lc = 0;
#pragma unroll
  for (int i = 0; i < 8; i++) { vals[i] = (m[base + i] != 0); lc += vals[i]; }
  cnt[t] = lc;
  __syncthreads();
  for (int off = 1; off < 256; off <<= 1) {
    int v = (t >= off) ? cnt[t - off] : 0;
    __syncthreads();
    cnt[t] += v;
    __syncthreads();
  }
  int pos = cnt[t] - lc;
  const int total = cnt[255];
#pragma unroll
  for (int i = 0; i < 8; i++)
    if (vals[i]) sidx[pos++] = base + i;
  for (int j = total + t; j < 2048; j += 256) sidx[j] = 0;
  if (t == 0) g_NK[b] = total;
}

// ---------------------------------------------------------------------------
// proj: grid 3584. [0,1024) K compacted; [1024,2048) Q (pre-scaled);
// [2048,3072) V compacted+transposed; [3072,3584) Wo f32->bf16.
// ---------------------------------------------------------------------------
__global__ __launch_bounds__(256) void proj_kernel(
    const float* __restrict__ keys, const float* __restrict__ query,
    const float* __restrict__ values,
    const float* __restrict__ Wk, const float* __restrict__ Wq,
    const float* __restrict__ Wv, const float* __restrict__ Wo,
    short* __restrict__ Kp, short* __restrict__ Qp, short* __restrict__ Vt,
    short* __restrict__ WoB) {
  const int bid0 = blockIdx.x;
  const int t = threadIdx.x;
  if (bid0 >= 3072) {   // Wo conversion tail
    int i = ((bid0 - 3072) * 256 + t) * 8;
    float4 a = *(const float4*)(Wo + i), b2 = *(const float4*)(Wo + i + 4);
    *(bf16x8*)(WoB + i) = cvt8(a, b2);
    return;
  }
  const int w = t >> 6, l = t & 63, l15 = l & 15, l4 = l >> 4;
  __shared__ short Al[64 * 64];
  __shared__ short Bl[64 * 64];
  __shared__ short Tl[64 * 66];

  if (bid0 < 2048) {
    int bid = bid0;
    const float* X = keys; const float* W = Wk; short* O = Kp;
    bool isq = false;
    if (bid >= 1024) { X = query; W = Wq; O = Qp; bid -= 1024; isq = true; }
    const int r0 = bid << 6;
    const int bb = r0 >> 15;
    if (!isq) {
      const int j0 = (r0 >> 4) & 2047;
      const int jlim = (g_NK[bb] + 63) & ~63;
      if (j0 >= jlim) return;
    }
#pragma unroll
    for (int i = 0; i < 2; i++) {
      int c = t + (i << 8);
      int row = c >> 3, col8 = c & 7;
      int pc = col8 ^ (row & 7);
      int ri = r0 + row;
      int j = (ri >> 4) & 2047, hh = ri & 15;
      int s = isq ? j : g_srcidx[(bb << 11) + j];
      const float* xs = X + ((size_t)((bb * 2048 + s) * 16 + hh)) * 64 + col8 * 8;
      float4 a0 = *(const float4*)xs, a1 = *(const float4*)(xs + 4);
      *(bf16x8*)&Al[row * 64 + pc * 8] = cvt8(a0, a1);
      const float* wsrc = W + row * 64 + col8 * 8;
      float4 b0 = *(const float4*)wsrc, b1 = *(const float4*)(wsrc + 4);
      *(bf16x8*)&Bl[row * 64 + pc * 8] = cvt8(b0, b1);
    }
    __syncthreads();
    f32x4 acc[4];
#pragma unroll
    for (int i = 0; i < 4; i++) acc[i] = (f32x4){0.f, 0.f, 0.f, 0.f};
#pragma unroll
    for (int kc = 0; kc < 2; kc++) {
      int ar = w * 16 + l15;
      bf16x8 af = *(const bf16x8*)((const char*)Al +
          ((ar * 128 + kc * 64 + l4 * 16) ^ ((ar & 7) << 4)));
#pragma unroll
      for (int ng = 0; ng < 4; ng++) {
        int br = ng * 16 + l15;
        bf16x8 bfr = *(const bf16x8*)((const char*)Bl +
            ((br * 128 + kc * 64 + l4 * 16) ^ ((br & 7) << 4)));
        acc[ng] = __builtin_amdgcn_mfma_f32_16x16x32_bf16(af, bfr, acc[ng], 0, 0, 0);
      }
    }
    const float osc = isq ? (1.4426950408889634f / 32.0f) : 1.0f;
#pragma unroll
    for (int ng = 0; ng < 4; ng++) {
#pragma unroll
      for (int j = 0; j < 4; j++) {
        int ri = r0 + w * 16 + l4 * 4 + j;
        int e = ng * 16 + l15;
        int b2 = ri >> 15, jj = (ri >> 4) & 2047, hh = ri & 15;
        O[(((size_t)(b2 * 16 + hh)) * 2048 + jj) * 64 + e] = f2bf(acc[ng][j] * osc);
      }
    }
  } else {
    const int bid = bid0 - 2048;
    const int st = bid & 31, bh = bid >> 5;
    const int b = bh >> 4, h = bh & 15;
    const int s0 = st << 6;
    const int jlim = (g_NK[b] + 63) & ~63;
    if (s0 >= jlim) return;
#pragma unroll
    for (int i = 0; i < 2; i++) {
      int c = t + (i << 8);
      int row = c >> 3, col8 = c & 7;
      int pc = col8 ^ (row & 7);
      int s = g_srcidx[(b << 11) + s0 + row];
      const float* xs = values + ((size_t)(b * 2048 + s)) * 1024 + h * 64 + col8 * 8;
      float4 a0 = *(const float4*)xs, a1 = *(const float4*)(xs + 4);
      *(bf16x8*)&Al[row * 64 + pc * 8] = cvt8(a0, a1);
      const float* wsrc = Wv + row * 64 + col8 * 8;
      float4 b0 = *(const float4*)wsrc, b1 = *(const float4*)(wsrc + 4);
      *(bf16x8*)&Bl[row * 64 + pc * 8] = cvt8(b0, b1);
    }
    __syncthreads();
    f32x4 acc[4];
#pragma unroll
    for (int i = 0; i < 4; i++) acc[i] = (f32x4){0.f, 0.f, 0.f, 0.f};
#pragma unroll
    for (int kc = 0; kc < 2; kc++) {
      int ar = w * 16 + l15;
      bf16x8 af = *(const bf16x8*)((const char*)Al +
          ((ar * 128 + kc * 64 + l4 * 16) ^ ((ar & 7) << 4)));
#pragma unroll
      for (int ng = 0; ng < 4; ng++) {
        int br = ng * 16 + l15;
        bf16x8 bfr = *(const bf16x8*)((const char*)Bl +
            ((br * 128 + kc * 64 + l4 * 16) ^ ((br & 7) << 4)));
        acc[ng] = __builtin_amdgcn_mfma_f32_16x16x32_bf16(af, bfr, acc[ng], 0, 0, 0);
      }
    }
#pragma unroll
    for (int ng = 0; ng < 4; ng++) {
#pragma unroll
      for (int j = 0; j < 4; j++) {
        Tl[(w * 16 + l4 * 4 + j) * 66 + ng * 16 + l15] = f2bf(acc[ng][j]);
      }
    }
    __syncthreads();
    int e = t >> 2, sc = (t & 3) << 4;
    bf16x8 o0, o1;
#pragma unroll
    for (int i = 0; i < 8; i++) {
      o0[i] = Tl[(sc + i) * 66 + e];
      o1[i] = Tl[(sc + 8 + i) * 66 + e];
    }
    short* dst = Vt + ((size_t)bh * 64 + e) * 2048 + s0 + sc;
    *(bf16x8*)dst = o0;
    *(bf16x8*)(dst + 8) = o1;
  }
}

// ---------------------------------------------------------------------------
// attn: swapped QK^T, 32x32x16 MFMA, compacted keys. Quad-buffered gll
// staging, 2 k-tiles per barrier. 8 waves x 32q = 256 q-rows/block,
// grid 256 (8 qb x 32 bh), XCD swizzle. Waves 0-3 stage K, 4-7 stage V.
// ---------------------------------------------------------------------------
__global__ __launch_bounds__(512) void attn_kernel(
    const short* __restrict__ Qp, const short* __restrict__ Kp,
    const short* __restrict__ Vt, short* __restrict__ AO) {
  const int bid = (int)(blockIdx.x % 8) * 32 + (int)(blockIdx.x / 8);
  const int qb = bid & 7, bh = bid >> 3;
  const int b = bh >> 4, h = bh & 15;
  const int t = threadIdx.x;
  const int w = t >> 6, l = t & 63, l31 = l & 31, hi = l >> 5;
  const int q0w = qb * 256 + w * 32;

  __shared__ short Kl[4][64 * 64];   // [k][d] swizzled, quad-buffered
  __shared__ short Vl[4][64 * 64];   // [d][k] swizzled, quad-buffered
  __shared__ float Cl[8 * 32];

  const short* Kbase = Kp + (size_t)bh * 2048 * 64;
  const short* Vbase = Vt + (size_t)bh * 64 * 2048;

  const int nk = g_NK[b];
  const int ntiles = (nk + 63) >> 6;

  // Q fragments: B-operand, lane holds col q = l31, d = dc*16 + hi*8 + e
  const short* qptr = Qp + ((size_t)bh * 2048 + q0w + l31) * 64 + hi * 8;
  bf16x8 qf[4];
#pragma unroll
  for (int dc = 0; dc < 4; dc++) qf[dc] = *(const bf16x8*)(qptr + dc * 16);

  // LDS fragment byte addrs: row x*32+l31, chunk (c2*2+hi) ^ (row&7)
  int laddr[2][4];
#pragma unroll
  for (int x = 0; x < 2; x++) {
    int rr = x * 32 + l31;
#pragma unroll
    for (int c2 = 0; c2 < 4; c2++)
      laddr[x][c2] = rr * 128 + (((c2 * 32) + hi * 16) ^ ((rr & 7) << 4));
  }

  // gll staging: half-block split. tt in [0,256): waves 0-3 -> K, 4-7 -> V.
  const int sh = t >> 8, tt = t & 255;
  const int srow = tt >> 3, scol = tt & 7;
  const int sc0 = (scol ^ (srow & 7)) * 8;
  const short* src0;
  const short* src1;
  short* dlds;
  if (sh == 0) {
    src0 = Kbase + srow * 64 + sc0;
    src1 = Kbase + (srow + 32) * 64 + sc0;
    dlds = &Kl[0][0];
  } else {
    src0 = Vbase + (size_t)srow * 2048 + sc0;
    src1 = Vbase + (size_t)(srow + 32) * 2048 + sc0;
    dlds = &Vl[0][0];
  }
  const int step0 = (sh == 0) ? 4096 : 64;   // per-tile source stride (shorts)
  const int d0 = tt * 8, d1 = tt * 8 + 2048;

  float sxa[8];
#pragma unroll
  for (int i = 0; i < 8; i++) sxa[i] = 0.f;
  f32x16 o0, o1;
#pragma unroll
  for (int r = 0; r < 16; r++) { o0[r] = 0.f; o1[r] = 0.f; }

  auto stage = [&](int kt, int bufi) {   // tile kt -> buffer bufi
    const int off = bufi << 12;          // 4096 shorts per buffer
    gll16(src0 + (size_t)kt * step0, dlds + off + d0);
    gll16(src1 + (size_t)kt * step0, dlds + off + d1);
  };

  auto compute = [&](int kt, int bufi) {
    const int bsb = bufi << 13;          // byte offset of buffer
    f32x16 st0, st1;
#pragma unroll
    for (int r = 0; r < 16; r++) { st0[r] = 0.f; st1[r] = 0.f; }
    __builtin_amdgcn_s_setprio(1);
#pragma unroll
    for (int dc = 0; dc < 4; dc++) {
      bf16x8 ka = *(const bf16x8*)((const char*)Kl + bsb + laddr[0][dc]);
      st0 = __builtin_amdgcn_mfma_f32_32x32x16_bf16(ka, qf[dc], st0, 0, 0, 0);
    }
#pragma unroll
    for (int dc = 0; dc < 4; dc++) {
      bf16x8 kb = *(const bf16x8*)((const char*)Kl + bsb + laddr[1][dc]);
      st1 = __builtin_amdgcn_mfma_f32_32x32x16_bf16(kb, qf[dc], st1, 0, 0, 0);
    }
    __builtin_amdgcn_s_setprio(0);

    // p = exp2(st)  (Q pre-scaled by log2e/32; m=0 fixed)
    if (((kt << 6) + 64) <= nk) {
#pragma unroll
      for (int r = 0; r < 16; r++) {
        st0[r] = __builtin_amdgcn_exp2f(st0[r]);
        st1[r] = __builtin_amdgcn_exp2f(st1[r]);
      }
    } else {
      const int kb2 = kt << 6;
#pragma unroll
      for (int r = 0; r < 16; r++) {
        int cr = (r & 3) + 8 * (r >> 2) + 4 * hi;
        float e0 = __builtin_amdgcn_exp2f(st0[r]);
        float e1 = __builtin_amdgcn_exp2f(st1[r]);
        st0[r] = (kb2 + cr < nk) ? e0 : 0.f;
        st1[r] = (kb2 + 32 + cr < nk) ? e1 : 0.f;
      }
    }

    // deferred row-sum partials
#pragma unroll
    for (int i = 0; i < 8; i++)
      sxa[i] += (st0[2 * i] + st0[2 * i + 1]) + (st1[2 * i] + st1[2 * i + 1]);

    // PV A-frags: pa[kc] covers k = kc*16 + hi*8 + 0..7
    bf16x8 pa[4];
#pragma unroll
    for (int kc = 0; kc < 4; kc++) {
      int bse = (kc & 1) * 8;
      float p0, p1, p2, p3, p4, p5, p6, p7;
      if (kc < 2) {
        p0 = st0[bse + 0]; p1 = st0[bse + 1]; p2 = st0[bse + 2]; p3 = st0[bse + 3];
        p4 = st0[bse + 4]; p5 = st0[bse + 5]; p6 = st0[bse + 6]; p7 = st0[bse + 7];
      } else {
        p0 = st1[bse + 0]; p1 = st1[bse + 1]; p2 = st1[bse + 2]; p3 = st1[bse + 3];
        p4 = st1[bse + 4]; p5 = st1[bse + 5]; p6 = st1[bse + 6]; p7 = st1[bse + 7];
      }
      int A0 = pack2(p0, p1), A1 = pack2(p2, p3);
      int B0 = pack2(p4, p5), B1 = pack2(p6, p7);
      plsw(A0, B0);
      plsw(A1, B1);
      union { int4 i; bf16x8 h; } u;
      u.i = make_int4(A0, A1, B0, B1);
      pa[kc] = u.h;
    }

    // PV: O[q][d] += P * V
    __builtin_amdgcn_s_setprio(1);
#pragma unroll
    for (int kc = 0; kc < 4; kc++) {
      bf16x8 vf = *(const bf16x8*)((const char*)Vl + bsb + laddr[0][kc]);
      o0 = __builtin_amdgcn_mfma_f32_32x32x16_bf16(pa[kc], vf, o0, 0, 0, 0);
    }
#pragma unroll
    for (int kc = 0; kc < 4; kc++) {
      bf16x8 vf = *(const bf16x8*)((const char*)Vl + bsb + laddr[1][kc]);
      o1 = __builtin_amdgcn_mfma_f32_32x32x16_bf16(pa[kc], vf, o1, 0, 0, 0);
    }
    __builtin_amdgcn_s_setprio(0);
  };

  // prologue: stage tiles 0,1 into buffers 0,1
  stage(0, 0);
  if (ntiles > 1) stage(1, 1);
  __syncthreads();

  for (int kt = 0; kt < ntiles; kt += 2) {
    const int p = (kt >> 1) & 1;
    const int cb = p * 2;          // current buffer pair
    const int nb = (1 - p) * 2;    // prefetch pair (fully consumed last iter)
    if (kt + 2 < ntiles) stage(kt + 2, nb);
    if (kt + 3 < ntiles) stage(kt + 3, nb + 1);
    compute(kt, cb);
    if (kt + 1 < ntiles) compute(kt + 1, cb + 1);
    __syncthreads();               // one barrier per 2 tiles
  }

  // final row-sum reduction (once, not per tile)
#pragma unroll
  for (int s2 = 4; s2 > 0; s2 >>= 1)
#pragma unroll
    for (int i = 0; i < 4; i++)
      if (i < s2) sxa[i] += sxa[i + s2];
  float l_run = pl_comb_add(sxa[0]);

  // epilogue: normalize + store
  float invr = 1.0f / l_run;
  Cl[w * 32 + l31] = invr;
  short* aob = AO + ((size_t)(b * 2048 + q0w)) * 1024 + h * 64 + l31;
#pragma unroll
  for (int r = 0; r < 16; r++) {
    int qr = (r & 3) + 8 * (r >> 2) + 4 * hi;
    float ic = Cl[w * 32 + qr];
    aob[(size_t)qr * 1024] = f2bf(o0[r] * ic);
    aob[(size_t)qr * 1024 + 32] = f2bf(o1[r] * ic);
  }
}

// ---------------------------------------------------------------------------
// outproj: 128x128 tile, grid 256 (32 mt x 8 nt), 512 threads = 8 waves
// (2x4; each wave 64x32 output). gll dbuf staging, XCD swizzle.
// ---------------------------------------------------------------------------
__global__ __launch_bounds__(512) void outproj_kernel(
    const short* __restrict__ AO, const short* __restrict__ WoB,
    const float* __restrict__ bo, float* __restrict__ Cout) {
  const int bid = (int)(blockIdx.x % 8) * 32 + (int)(blockIdx.x / 8);
  const int mt = bid >> 3, nt = bid & 7;
  const int m0 = mt << 7, n0 = nt << 7;
  const int t = threadIdx.x;
  const int w = t >> 6, wr = w >> 2, wc = w & 3;   // 2x4 wave grid
  const int l = t & 63, l15 = l & 15, l4 = l >> 4;
  __shared__ short Al[2][128 * 64];
  __shared__ short Bl[2][128 * 64];

  const short* asrc[2];
  const short* bsrc[2];
  int ldst[2];
#pragma unroll
  for (int i = 0; i < 2; i++) {
    int c = t + (i << 9);
    int row = c >> 3, col8 = c & 7;
    int sc = (col8 ^ (row & 7)) * 8;
    asrc[i] = AO + (size_t)(m0 + row) * 1024 + sc;
    bsrc[i] = WoB + (size_t)(n0 + row) * 1024 + sc;
    ldst[i] = c * 8;
  }
  short* al = &Al[0][0];
  short* bl = &Bl[0][0];

  auto stage = [&](int ks, int bs) {
    const int nb = bs << 13;   // 8192 shorts per buffer
    const int ko = ks * 64;
#pragma unroll
    for (int i = 0; i < 2; i++) {
      gll16(asrc[i] + ko, al + nb + ldst[i]);
      gll16(bsrc[i] + ko, bl + nb + ldst[i]);
    }
  };

  stage(0, 0);
  __syncthreads();

  f32x4 acc[4][2];
#pragma unroll
  for (int mi = 0; mi < 4; mi++)
#pragma unroll
    for (int ni = 0; ni < 2; ni++) acc[mi][ni] = (f32x4){0.f, 0.f, 0.f, 0.f};

  for (int ks = 0; ks < 16; ks++) {
    const int bs = ks & 1, bsb = bs << 14;   // byte offset (16384 B/buffer)
    if (ks < 15) stage(ks + 1, bs ^ 1);
#pragma unroll
    for (int kc = 0; kc < 2; kc++) {
      bf16x8 af[4];
#pragma unroll
      for (int mi = 0; mi < 4; mi++) {
        int ar = wr * 64 + mi * 16 + l15;
        af[mi] = *(const bf16x8*)((const char*)Al + bsb +
            ((ar * 128 + kc * 64 + l4 * 16) ^ ((ar & 7) << 4)));
      }
#pragma unroll
      for (int ni = 0; ni < 2; ni++) {
        int br = wc * 32 + ni * 16 + l15;
        bf16x8 bfr = *(const bf16x8*)((const char*)Bl + bsb +
            ((br * 128 + kc * 64 + l4 * 16) ^ ((br & 7) << 4)));
#pragma unroll
        for (int mi = 0; mi < 4; mi++)
          acc[mi][ni] = __builtin_amdgcn_mfma_f32_16x16x32_bf16(
              af[mi], bfr, acc[mi][ni], 0, 0, 0);
      }
    }
    __syncthreads();
  }

#pragma unroll
  for (int ni = 0; ni < 2; ni++) {
    int n = n0 + wc * 32 + ni * 16 + l15;
    float bias = bo[n];
#pragma unroll
    for (int mi = 0; mi < 4; mi++) {
#pragma unroll
      for (int j = 0; j < 4; j++) {
        int m = m0 + wr * 64 + mi * 16 + l4 * 4 + j;
        Cout[(size_t)m * 1024 + n] = acc[mi][ni][j] + bias;
      }
    }
  }
}

// ---------------------------------------------------------------------------
extern "C" void kernel_launch(void* const* d_in, const int* in_sizes, int n_in,
                              void* d_out, int out_size, void* d_ws, size_t ws_size,
                              hipStream_t stream) {
  const float* values = (const float*)d_in[0];
  const float* keys   = (const float*)d_in[1];
  const float* query  = (const float*)d_in[2];
  const int*   mask   = (const int*)d_in[3];
  const float* Wv = (const float*)d_in[4];
  const float* Wk = (const float*)d_in[5];
  const float* Wq = (const float*)d_in[6];
  const float* Wo = (const float*)d_in[7];
  const float* bo = (const float*)d_in[8];
  float* out = (float*)d_out;
  char* ws = (char*)d_ws;
  short* Qp  = (short*)(ws + (size_t)0);
  short* Kp  = (short*)(ws + ((size_t)8 << 20));
  short* Vtp = (short*)(ws + ((size_t)16 << 20));
  short* AO  = (short*)(ws + ((size_t)24 << 20));
  short* WoB = (short*)(ws + ((size_t)32 << 20));

  prep_kernel<<<2, 256, 0, stream>>>(mask);
  proj_kernel<<<3584, 256, 0, stream>>>(keys, query, values, Wk, Wq, Wv, Wo,
                                        Kp, Qp, Vtp, WoB);
  attn_kernel<<<256, 512, 0, stream>>>(Qp, Kp, Vtp, AO);
  outproj_kernel<<<256, 512, 0, stream>>>(AO, WoB, bo, out);
}

// Round 22
// 64.854 us; speedup vs baseline: 1.0039x; 1.0039x over previous
//
#include <hip/hip_runtime.h>
#include <hip/hip_bf16.h>

// SelfAttention: B=2, S=2048, E=1024, H=16, D=64
// FINAL = R20/R18 configuration (best measured: 64.90 us; reproduced 65.0+-0.4
// across R18/R19/R20/R21). 185.4 us (R1 baseline) -> 64.9 us, 2.86x.
//   prep    : 2 blocks, per-batch mask scan -> g_srcidx/g_NK
//   proj    : K(compacted), Q(pre-scaled log2e/32), V(compacted,T), Wo->bf16
//   attn    : swapped-QK^T, 32x32x16 MFMA, m=0, in-register softmax,
//             gll dbuf staging (both-sides XOR swizzle), 8-wave 256q blocks,
//             XCD swizzle, setprio around MFMA clusters
//   outproj : [4096,1024] @ WoB^T + bo -> f32, 128^2 tile, XCD swizzle
// attn ledger (10 experiments): XCD swizzle +2.3us; quad-buf x2 / split-K /
// counted-vmcnt / Q-fuse / direct-global / tri-buf / sum-hoist / 256q /
// setprio-removal all null-or-regress. Structure floor reached.

typedef __attribute__((ext_vector_type(8))) short bf16x8;
typedef __attribute__((ext_vector_type(4))) float f32x4;
typedef __attribute__((ext_vector_type(16))) float f32x16;
typedef __attribute__((ext_vector_type(2))) int i32x2;

__device__ int g_srcidx[2 * 2048];
__device__ int g_NK[2];

__device__ __forceinline__ short f2bf(float x) {
  union { float f; unsigned u; } v; v.f = x;
  unsigned r = v.u + 0x7FFFu + ((v.u >> 16) & 1u);
  return (short)(r >> 16);
}

// pair pack via compiler-recognized cast -> v_cvt_pk_bf16_f32 (RNE)
__device__ __forceinline__ int pack2(float lo, float hi) {
  __hip_bfloat162 h = __float22bfloat162_rn(make_float2(lo, hi));
  int r; __builtin_memcpy(&r, &h, 4); return r;
}

__device__ __forceinline__ bf16x8 cvt8(float4 a, float4 b) {
  union { int i[4]; bf16x8 h; } u;
  u.i[0] = pack2(a.x, a.y);
  u.i[1] = pack2(a.z, a.w);
  u.i[2] = pack2(b.x, b.y);
  u.i[3] = pack2(b.z, b.w);
  return u.h;
}

__device__ __forceinline__ void plsw(int& a, int& b) {
  i32x2 r = __builtin_amdgcn_permlane32_swap(a, b, false, false);
  a = r[0]; b = r[1];
}
__device__ __forceinline__ float pl_comb_add(float v) {
  int a = __float_as_int(v), b = a;
  i32x2 r = __builtin_amdgcn_permlane32_swap(a, b, false, false);
  return __int_as_float(r[0]) + __int_as_float(r[1]);
}

// async global->LDS, 16B per lane; LDS dest must be wave-linear (base+lane*16)
__device__ __forceinline__ void gll16(const short* g, short* l) {
  __builtin_amdgcn_global_load_lds(
      (const __attribute__((address_space(1))) void*)g,
      (__attribute__((address_space(3))) void*)l, 16, 0, 0);
}

// ---------------------------------------------------------------------------
// prep: per-batch mask scan only (2 blocks).
// ---------------------------------------------------------------------------
__global__ __launch_bounds__(256) void prep_kernel(const int* __restrict__ mask) {
  __shared__ int cnt[256];
  const int t = threadIdx.x;
  const int b = blockIdx.x;
  const int* m = mask + b * 2048;
  int* sidx = g_srcidx + b * 2048;
  const int base = t * 8;
  int vals[8], lc = 0;
#pragma unroll
  for (int i = 0; i < 8; i++) { vals[i] = (m[base + i] != 0); lc += vals[i]; }
  cnt[t] = lc;
  __syncthreads();
  for (int off = 1; off < 256; off <<= 1) {
    int v = (t >= off) ? cnt[t - off] : 0;
    __syncthreads();
    cnt[t] += v;
    __syncthreads();
  }
  int pos = cnt[t] - lc;
  const int total = cnt[255];
#pragma unroll
  for (int i = 0; i < 8; i++)
    if (vals[i]) sidx[pos++] = base + i;
  for (int j = total + t; j < 2048; j += 256) sidx[j] = 0;
  if (t == 0) g_NK[b] = total;
}

// ---------------------------------------------------------------------------
// proj: grid 3584. [0,1024) K compacted; [1024,2048) Q (pre-scaled);
// [2048,3072) V compacted+transposed; [3072,3584) Wo f32->bf16.
// ---------------------------------------------------------------------------
__global__ __launch_bounds__(256) void proj_kernel(
    const float* __restrict__ keys, const float* __restrict__ query,
    const float* __restrict__ values,
    const float* __restrict__ Wk, const float* __restrict__ Wq,
    const float* __restrict__ Wv, const float* __restrict__ Wo,
    short* __restrict__ Kp, short* __restrict__ Qp, short* __restrict__ Vt,
    short* __restrict__ WoB) {
  const int bid0 = blockIdx.x;
  const int t = threadIdx.x;
  if (bid0 >= 3072) {   // Wo conversion tail
    int i = ((bid0 - 3072) * 256 + t) * 8;
    float4 a = *(const float4*)(Wo + i), b2 = *(const float4*)(Wo + i + 4);
    *(bf16x8*)(WoB + i) = cvt8(a, b2);
    return;
  }
  const int w = t >> 6, l = t & 63, l15 = l & 15, l4 = l >> 4;
  __shared__ short Al[64 * 64];
  __shared__ short Bl[64 * 64];
  __shared__ short Tl[64 * 66];

  if (bid0 < 2048) {
    int bid = bid0;
    const float* X = keys; const float* W = Wk; short* O = Kp;
    bool isq = false;
    if (bid >= 1024) { X = query; W = Wq; O = Qp; bid -= 1024; isq = true; }
    const int r0 = bid << 6;
    const int bb = r0 >> 15;
    if (!isq) {
      const int j0 = (r0 >> 4) & 2047;
      const int jlim = (g_NK[bb] + 63) & ~63;
      if (j0 >= jlim) return;
    }
#pragma unroll
    for (int i = 0; i < 2; i++) {
      int c = t + (i << 8);
      int row = c >> 3, col8 = c & 7;
      int pc = col8 ^ (row & 7);
      int ri = r0 + row;
      int j = (ri >> 4) & 2047, hh = ri & 15;
      int s = isq ? j : g_srcidx[(bb << 11) + j];
      const float* xs = X + ((size_t)((bb * 2048 + s) * 16 + hh)) * 64 + col8 * 8;
      float4 a0 = *(const float4*)xs, a1 = *(const float4*)(xs + 4);
      *(bf16x8*)&Al[row * 64 + pc * 8] = cvt8(a0, a1);
      const float* wsrc = W + row * 64 + col8 * 8;
      float4 b0 = *(const float4*)wsrc, b1 = *(const float4*)(wsrc + 4);
      *(bf16x8*)&Bl[row * 64 + pc * 8] = cvt8(b0, b1);
    }
    __syncthreads();
    f32x4 acc[4];
#pragma unroll
    for (int i = 0; i < 4; i++) acc[i] = (f32x4){0.f, 0.f, 0.f, 0.f};
#pragma unroll
    for (int kc = 0; kc < 2; kc++) {
      int ar = w * 16 + l15;
      bf16x8 af = *(const bf16x8*)((const char*)Al +
          ((ar * 128 + kc * 64 + l4 * 16) ^ ((ar & 7) << 4)));
#pragma unroll
      for (int ng = 0; ng < 4; ng++) {
        int br = ng * 16 + l15;
        bf16x8 bfr = *(const bf16x8*)((const char*)Bl +
            ((br * 128 + kc * 64 + l4 * 16) ^ ((br & 7) << 4)));
        acc[ng] = __builtin_amdgcn_mfma_f32_16x16x32_bf16(af, bfr, acc[ng], 0, 0, 0);
      }
    }
    const float osc = isq ? (1.4426950408889634f / 32.0f) : 1.0f;
#pragma unroll
    for (int ng = 0; ng < 4; ng++) {
#pragma unroll
      for (int j = 0; j < 4; j++) {
        int ri = r0 + w * 16 + l4 * 4 + j;
        int e = ng * 16 + l15;
        int b2 = ri >> 15, jj = (ri >> 4) & 2047, hh = ri & 15;
        O[(((size_t)(b2 * 16 + hh)) * 2048 + jj) * 64 + e] = f2bf(acc[ng][j] * osc);
      }
    }
  } else {
    const int bid = bid0 - 2048;
    const int st = bid & 31, bh = bid >> 5;
    const int b = bh >> 4, h = bh & 15;
    const int s0 = st << 6;
    const int jlim = (g_NK[b] + 63) & ~63;
    if (s0 >= jlim) return;
#pragma unroll
    for (int i = 0; i < 2; i++) {
      int c = t + (i << 8);
      int row = c >> 3, col8 = c & 7;
      int pc = col8 ^ (row & 7);
      int s = g_srcidx[(b << 11) + s0 + row];
      const float* xs = values + ((size_t)(b * 2048 + s)) * 1024 + h * 64 + col8 * 8;
      float4 a0 = *(const float4*)xs, a1 = *(const float4*)(xs + 4);
      *(bf16x8*)&Al[row * 64 + pc * 8] = cvt8(a0, a1);
      const float* wsrc = Wv + row * 64 + col8 * 8;
      float4 b0 = *(const float4*)wsrc, b1 = *(const float4*)(wsrc + 4);
      *(bf16x8*)&Bl[row * 64 + pc * 8] = cvt8(b0, b1);
    }
    __syncthreads();
    f32x4 acc[4];
#pragma unroll
    for (int i = 0; i < 4; i++) acc[i] = (f32x4){0.f, 0.f, 0.f, 0.f};
#pragma unroll
    for (int kc = 0; kc < 2; kc++) {
      int ar = w * 16 + l15;
      bf16x8 af = *(const bf16x8*)((const char*)Al +
          ((ar * 128 + kc * 64 + l4 * 16) ^ ((ar & 7) << 4)));
#pragma unroll
      for (int ng = 0; ng < 4; ng++) {
        int br = ng * 16 + l15;
        bf16x8 bfr = *(const bf16x8*)((const char*)Bl +
            ((br * 128 + kc * 64 + l4 * 16) ^ ((br & 7) << 4)));
        acc[ng] = __builtin_amdgcn_mfma_f32_16x16x32_bf16(af, bfr, acc[ng], 0, 0, 0);
      }
    }
#pragma unroll
    for (int ng = 0; ng < 4; ng++) {
#pragma unroll
      for (int j = 0; j < 4; j++) {
        Tl[(w * 16 + l4 * 4 + j) * 66 + ng * 16 + l15] = f2bf(acc[ng][j]);
      }
    }
    __syncthreads();
    int e = t >> 2, sc = (t & 3) << 4;
    bf16x8 o0, o1;
#pragma unroll
    for (int i = 0; i < 8; i++) {
      o0[i] = Tl[(sc + i) * 66 + e];
      o1[i] = Tl[(sc + 8 + i) * 66 + e];
    }
    short* dst = Vt + ((size_t)bh * 64 + e) * 2048 + s0 + sc;
    *(bf16x8*)dst = o0;
    *(bf16x8*)(dst + 8) = o1;
  }
}

// ---------------------------------------------------------------------------
// attn: swapped QK^T, 32x32x16 MFMA, compacted keys, gll dbuf staging.
// 8 waves x 32q = 256 q-rows/block, grid 256 (8 qb x 32 bh), XCD swizzle.
// Waves 0-3 stage K, waves 4-7 stage V (2 gll16/thread/tile).
// ---------------------------------------------------------------------------
__global__ __launch_bounds__(512) void attn_kernel(
    const short* __restrict__ Qp, const short* __restrict__ Kp,
    const short* __restrict__ Vt, short* __restrict__ AO) {
  const int bid = (int)(blockIdx.x % 8) * 32 + (int)(blockIdx.x / 8);
  const int qb = bid & 7, bh = bid >> 3;
  const int b = bh >> 4, h = bh & 15;
  const int t = threadIdx.x;
  const int w = t >> 6, l = t & 63, l31 = l & 31, hi = l >> 5;
  const int q0w = qb * 256 + w * 32;

  __shared__ short Kl[2][64 * 64];   // [k][d] swizzled, dbuf (8 KB each)
  __shared__ short Vl[2][64 * 64];   // [d][k] swizzled, dbuf
  __shared__ float Cl[8 * 32];

  const short* Kbase = Kp + (size_t)bh * 2048 * 64;
  const short* Vbase = Vt + (size_t)bh * 64 * 2048;

  const int nk = g_NK[b];
  const int ntiles = (nk + 63) >> 6;

  // Q fragments: B-operand, lane holds col q = l31, d = dc*16 + hi*8 + e
  const short* qptr = Qp + ((size_t)bh * 2048 + q0w + l31) * 64 + hi * 8;
  bf16x8 qf[4];
#pragma unroll
  for (int dc = 0; dc < 4; dc++) qf[dc] = *(const bf16x8*)(qptr + dc * 16);

  // LDS fragment byte addrs: row x*32+l31, chunk (c2*2+hi) ^ (row&7)
  int laddr[2][4];
#pragma unroll
  for (int x = 0; x < 2; x++) {
    int rr = x * 32 + l31;
#pragma unroll
    for (int c2 = 0; c2 < 4; c2++)
      laddr[x][c2] = rr * 128 + (((c2 * 32) + hi * 16) ^ ((rr & 7) << 4));
  }

  // gll staging: half-block split. tt in [0,256): waves 0-3 -> K, 4-7 -> V.
  const int sh = t >> 8, tt = t & 255;
  const int srow = tt >> 3, scol = tt & 7;
  const int sc0 = (scol ^ (srow & 7)) * 8;
  const short* src0;
  const short* src1;
  short* dlds;
  if (sh == 0) {
    src0 = Kbase + srow * 64 + sc0;
    src1 = Kbase + (srow + 32) * 64 + sc0;
    dlds = &Kl[0][0];
  } else {
    src0 = Vbase + (size_t)srow * 2048 + sc0;
    src1 = Vbase + (size_t)(srow + 32) * 2048 + sc0;
    dlds = &Vl[0][0];
  }
  const int step0 = (sh == 0) ? 4096 : 64;   // per-tile source stride (shorts)
  const int d0 = tt * 8, d1 = tt * 8 + 2048;

  // prologue: stage tile 0 into buf 0
  gll16(src0, dlds + d0);
  gll16(src1, dlds + d1);
  __syncthreads();

  float sxa[8];
#pragma unroll
  for (int i = 0; i < 8; i++) sxa[i] = 0.f;
  f32x16 o0, o1;
#pragma unroll
  for (int r = 0; r < 16; r++) { o0[r] = 0.f; o1[r] = 0.f; }

  for (int kt = 0; kt < ntiles; kt++) {
    const int bs = kt & 1;
    const int bsb = bs << 13;          // byte offset of current buffer
    if (kt + 1 < ntiles) {             // prefetch next tile into other buffer
      const int nb = (bs ^ 1) << 12;   // short offset
      gll16(src0 + (size_t)(kt + 1) * step0, dlds + nb + d0);
      gll16(src1 + (size_t)(kt + 1) * step0, dlds + nb + d1);
    }

    // QK^T swapped: ST[half][r] = S^T[k = half*32+(r&3)+8*(r>>2)+4*hi][q=l31]
    f32x16 st0, st1;
#pragma unroll
    for (int r = 0; r < 16; r++) { st0[r] = 0.f; st1[r] = 0.f; }
    __builtin_amdgcn_s_setprio(1);
#pragma unroll
    for (int dc = 0; dc < 4; dc++) {
      bf16x8 ka = *(const bf16x8*)((const char*)Kl + bsb + laddr[0][dc]);
      st0 = __builtin_amdgcn_mfma_f32_32x32x16_bf16(ka, qf[dc], st0, 0, 0, 0);
    }
#pragma unroll
    for (int dc = 0; dc < 4; dc++) {
      bf16x8 kb = *(const bf16x8*)((const char*)Kl + bsb + laddr[1][dc]);
      st1 = __builtin_amdgcn_mfma_f32_32x32x16_bf16(kb, qf[dc], st1, 0, 0, 0);
    }
    __builtin_amdgcn_s_setprio(0);

    // p = exp2(st)  (Q pre-scaled by log2e/32; m=0 fixed)
    if (((kt << 6) + 64) <= nk) {
#pragma unroll
      for (int r = 0; r < 16; r++) {
        st0[r] = __builtin_amdgcn_exp2f(st0[r]);
        st1[r] = __builtin_amdgcn_exp2f(st1[r]);
      }
    } else {
      const int kb2 = kt << 6;
#pragma unroll
      for (int r = 0; r < 16; r++) {
        int cr = (r & 3) + 8 * (r >> 2) + 4 * hi;
        float e0 = __builtin_amdgcn_exp2f(st0[r]);
        float e1 = __builtin_amdgcn_exp2f(st1[r]);
        st0[r] = (kb2 + cr < nk) ? e0 : 0.f;
        st1[r] = (kb2 + 32 + cr < nk) ? e1 : 0.f;
      }
    }

    // deferred row sum: accumulate per-lane partials; reduce after the loop
#pragma unroll
    for (int i = 0; i < 8; i++)
      sxa[i] += (st0[2 * i] + st0[2 * i + 1]) + (st1[2 * i] + st1[2 * i + 1]);

    // PV A-frags: pa[kc] covers k = kc*16 + hi*8 + 0..7
    bf16x8 pa[4];
#pragma unroll
    for (int kc = 0; kc < 4; kc++) {
      int bse = (kc & 1) * 8;
      float p0, p1, p2, p3, p4, p5, p6, p7;
      if (kc < 2) {
        p0 = st0[bse + 0]; p1 = st0[bse + 1]; p2 = st0[bse + 2]; p3 = st0[bse + 3];
        p4 = st0[bse + 4]; p5 = st0[bse + 5]; p6 = st0[bse + 6]; p7 = st0[bse + 7];
      } else {
        p0 = st1[bse + 0]; p1 = st1[bse + 1]; p2 = st1[bse + 2]; p3 = st1[bse + 3];
        p4 = st1[bse + 4]; p5 = st1[bse + 5]; p6 = st1[bse + 6]; p7 = st1[bse + 7];
      }
      int A0 = pack2(p0, p1), A1 = pack2(p2, p3);
      int B0 = pack2(p4, p5), B1 = pack2(p6, p7);
      plsw(A0, B0);
      plsw(A1, B1);
      union { int4 i; bf16x8 h; } u;
      u.i = make_int4(A0, A1, B0, B1);
      pa[kc] = u.h;
    }

    // PV: O[q][d] += P * V
    __builtin_amdgcn_s_setprio(1);
#pragma unroll
    for (int kc = 0; kc < 4; kc++) {
      bf16x8 vf = *(const bf16x8*)((const char*)Vl + bsb + laddr[0][kc]);
      o0 = __builtin_amdgcn_mfma_f32_32x32x16_bf16(pa[kc], vf, o0, 0, 0, 0);
    }
#pragma unroll
    for (int kc = 0; kc < 4; kc++) {
      bf16x8 vf = *(const bf16x8*)((const char*)Vl + bsb + laddr[1][kc]);
      o1 = __builtin_amdgcn_mfma_f32_32x32x16_bf16(pa[kc], vf, o1, 0, 0, 0);
    }
    __builtin_amdgcn_s_setprio(0);
    __syncthreads();   // drains vmcnt: next buffer ready
  }

  // final row-sum reduction (once, not per tile)
#pragma unroll
  for (int s2 = 4; s2 > 0; s2 >>= 1)
#pragma unroll
    for (int i = 0; i < 4; i++)
      if (i < s2) sxa[i] += sxa[i + s2];
  float l_run = pl_comb_add(sxa[0]);

  // epilogue: normalize + store
  float invr = 1.0f / l_run;
  Cl[w * 32 + l31] = invr;
  short* aob = AO + ((size_t)(b * 2048 + q0w)) * 1024 + h * 64 + l31;
#pragma unroll
  for (int r = 0; r < 16; r++) {
    int qr = (r & 3) + 8 * (r >> 2) + 4 * hi;
    float ic = Cl[w * 32 + qr];
    aob[(size_t)qr * 1024] = f2bf(o0[r] * ic);
    aob[(size_t)qr * 1024 + 32] = f2bf(o1[r] * ic);
  }
}

// ---------------------------------------------------------------------------
// outproj: 128x128 tile, grid 256 (32 mt x 8 nt), 512 threads = 8 waves
// (2x4; each wave 64x32 output). gll dbuf staging, XCD swizzle.
// ---------------------------------------------------------------------------
__global__ __launch_bounds__(512) void outproj_kernel(
    const short* __restrict__ AO, const short* __restrict__ WoB,
    const float* __restrict__ bo, float* __restrict__ Cout) {
  const int bid = (int)(blockIdx.x % 8) * 32 + (int)(blockIdx.x / 8);
  const int mt = bid >> 3, nt = bid & 7;
  const int m0 = mt << 7, n0 = nt << 7;
  const int t = threadIdx.x;
  const int w = t >> 6, wr = w >> 2, wc = w & 3;   // 2x4 wave grid
  const int l = t & 63, l15 = l & 15, l4 = l >> 4;
  __shared__ short Al[2][128 * 64];
  __shared__ short Bl[2][128 * 64];

  const short* asrc[2];
  const short* bsrc[2];
  int ldst[2];
#pragma unroll
  for (int i = 0; i < 2; i++) {
    int c = t + (i << 9);
    int row = c >> 3, col8 = c & 7;
    int sc = (col8 ^ (row & 7)) * 8;
    asrc[i] = AO + (size_t)(m0 + row) * 1024 + sc;
    bsrc[i] = WoB + (size_t)(n0 + row) * 1024 + sc;
    ldst[i] = c * 8;
  }
  short* al = &Al[0][0];
  short* bl = &Bl[0][0];

  auto stage = [&](int ks, int bs) {
    const int nb = bs << 13;   // 8192 shorts per buffer
    const int ko = ks * 64;
#pragma unroll
    for (int i = 0; i < 2; i++) {
      gll16(asrc[i] + ko, al + nb + ldst[i]);
      gll16(bsrc[i] + ko, bl + nb + ldst[i]);
    }
  };

  stage(0, 0);
  __syncthreads();

  f32x4 acc[4][2];
#pragma unroll
  for (int mi = 0; mi < 4; mi++)
#pragma unroll
    for (int ni = 0; ni < 2; ni++) acc[mi][ni] = (f32x4){0.f, 0.f, 0.f, 0.f};

  for (int ks = 0; ks < 16; ks++) {
    const int bs = ks & 1, bsb = bs << 14;   // byte offset (16384 B/buffer)
    if (ks < 15) stage(ks + 1, bs ^ 1);
#pragma unroll
    for (int kc = 0; kc < 2; kc++) {
      bf16x8 af[4];
#pragma unroll
      for (int mi = 0; mi < 4; mi++) {
        int ar = wr * 64 + mi * 16 + l15;
        af[mi] = *(const bf16x8*)((const char*)Al + bsb +
            ((ar * 128 + kc * 64 + l4 * 16) ^ ((ar & 7) << 4)));
      }
#pragma unroll
      for (int ni = 0; ni < 2; ni++) {
        int br = wc * 32 + ni * 16 + l15;
        bf16x8 bfr = *(const bf16x8*)((const char*)Bl + bsb +
            ((br * 128 + kc * 64 + l4 * 16) ^ ((br & 7) << 4)));
#pragma unroll
        for (int mi = 0; mi < 4; mi++)
          acc[mi][ni] = __builtin_amdgcn_mfma_f32_16x16x32_bf16(
              af[mi], bfr, acc[mi][ni], 0, 0, 0);
      }
    }
    __syncthreads();
  }

#pragma unroll
  for (int ni = 0; ni < 2; ni++) {
    int n = n0 + wc * 32 + ni * 16 + l15;
    float bias = bo[n];
#pragma unroll
    for (int mi = 0; mi < 4; mi++) {
#pragma unroll
      for (int j = 0; j < 4; j++) {
        int m = m0 + wr * 64 + mi * 16 + l4 * 4 + j;
        Cout[(size_t)m * 1024 + n] = acc[mi][ni][j] + bias;
      }
    }
  }
}

// ---------------------------------------------------------------------------
extern "C" void kernel_launch(void* const* d_in, const int* in_sizes, int n_in,
                              void* d_out, int out_size, void* d_ws, size_t ws_size,
                              hipStream_t stream) {
  const float* values = (const float*)d_in[0];
  const float* keys   = (const float*)d_in[1];
  const float* query  = (const float*)d_in[2];
  const int*   mask   = (const int*)d_in[3];
  const float* Wv = (const float*)d_in[4];
  const float* Wk = (const float*)d_in[5];
  const float* Wq = (const float*)d_in[6];
  const float* Wo = (const float*)d_in[7];
  const float* bo = (const float*)d_in[8];
  float* out = (float*)d_out;
  char* ws = (char*)d_ws;
  short* Qp  = (short*)(ws + (size_t)0);
  short* Kp  = (short*)(ws + ((size_t)8 << 20));
  short* Vtp = (short*)(ws + ((size_t)16 << 20));
  short* AO  = (short*)(ws + ((size_t)24 << 20));
  short* WoB = (short*)(ws + ((size_t)32 << 20));

  prep_kernel<<<2, 256, 0, stream>>>(mask);
  proj_kernel<<<3584, 256, 0, stream>>>(keys, query, values, Wk, Wq, Wv, Wo,
                                        Kp, Qp, Vtp, WoB);
  attn_kernel<<<256, 512, 0, stream>>>(Qp, Kp, Vtp, AO);
  outproj_kernel<<<256, 512, 0, stream>>>(AO, WoB, bo, out);
}